// Round 9
// baseline (116.631 us; speedup 1.0000x reference)
//
#include <hip/hip_runtime.h>
#include <hip/hip_bf16.h>

typedef __attribute__((ext_vector_type(8)))  short    s16x8;
typedef __attribute__((ext_vector_type(4)))  short    s16x4;
typedef __attribute__((ext_vector_type(16))) float    f32x16;
typedef __attribute__((ext_vector_type(4)))  unsigned u32x4;
typedef __attribute__((ext_vector_type(2)))  unsigned u32x2;

#define NB 4
#define NS 4096
#define ND 64
#define NTOK (NB*NS)
#define PERB (NS*ND)   // elements per batch per tensor

static __device__ __forceinline__ unsigned cvt_pk_bf16(float lo, float hi) {
    unsigned r;
    asm("v_cvt_pk_bf16_f32 %0, %1, %2" : "=v"(r) : "v"(lo), "v"(hi));
    return r;
}
static __device__ __forceinline__ float exp2_fast(float x) {
    float r;
    asm("v_exp_f32 %0, %1" : "=v"(r) : "v"(x));
    return r;
}
// async global->LDS, 16B per lane: lane L lands at lds_base + L*16
static __device__ __forceinline__ void gload_lds16(const __hip_bfloat16* g,
                                                   __hip_bfloat16* l) {
    __builtin_amdgcn_global_load_lds(
        (const __attribute__((address_space(1))) unsigned int*)g,
        (__attribute__((address_space(3))) unsigned int*)l, 16, 0, 0);
}

// ---------------------------------------------------------------------------
// MFMA projection (validated r8). One wave per 32-token tile, all 64 outputs.
//  Layouts produced (exactly what attn reads):
//   Q',K' [t][d]: (t>>5)*2048 + (d>>3)*256 + (t&31)*8 + (d&7)
//   V^T  [d][t]: (t>>6)*4096 + (d>>5)*2048 + ((t>>4)&3)*512 + ((t>>3)&1)*256
//                + (d&31)*8 + (t&7)
//  Scales folded: Q' *= qw/64*LOG2E, K' *= kw/64. Bias added in fp32.
// ---------------------------------------------------------------------------
__global__ __launch_bounds__(64) void proj_kernel(
    const float* __restrict__ q, const float* __restrict__ k, const float* __restrict__ v,
    const float* __restrict__ Wq, const float* __restrict__ bq,
    const float* __restrict__ Wk, const float* __restrict__ bk,
    const float* __restrict__ Wv, const float* __restrict__ bv,
    const float* __restrict__ qw, const float* __restrict__ kw,
    __hip_bfloat16* __restrict__ qf, __hip_bfloat16* __restrict__ kf,
    __hip_bfloat16* __restrict__ vf)
{
    const int which = blockIdx.y;
    const int lane = threadIdx.x;
    const int r31 = lane & 31, hi = lane >> 5;
    const int bx = blockIdx.x;                          // 32-token tile
    const float* X    = (which == 0) ? q  : (which == 1) ? k  : v;
    const float* W    = (which == 0) ? Wq : (which == 1) ? Wk : Wv;
    const float* bias = (which == 0) ? bq : (which == 1) ? bk : bv;

    const float* xrow = X + ((size_t)bx*32 + r31) * ND + 8*hi;
    s16x8 xf[4];
    #pragma unroll
    for (int c = 0; c < 4; ++c) {
        float4 f0 = *(const float4*)(xrow + 16*c);
        float4 f1 = *(const float4*)(xrow + 16*c + 4);
        u32x4 u = { cvt_pk_bf16(f0.x, f0.y), cvt_pk_bf16(f0.z, f0.w),
                    cvt_pk_bf16(f1.x, f1.y), cvt_pk_bf16(f1.z, f1.w) };
        xf[c] = __builtin_bit_cast(s16x8, u);
    }
    s16x8 wf[2][4];
    #pragma unroll
    for (int dt = 0; dt < 2; ++dt) {
        const float* wrow = W + (size_t)(32*dt + r31) * ND + 8*hi;
        #pragma unroll
        for (int c = 0; c < 4; ++c) {
            float4 f0 = *(const float4*)(wrow + 16*c);
            float4 f1 = *(const float4*)(wrow + 16*c + 4);
            u32x4 u = { cvt_pk_bf16(f0.x, f0.y), cvt_pk_bf16(f0.z, f0.w),
                        cvt_pk_bf16(f1.x, f1.y), cvt_pk_bf16(f1.z, f1.w) };
            wf[dt][c] = __builtin_bit_cast(s16x8, u);
        }
    }

    f32x16 acc0 = (f32x16)0.f, acc1 = (f32x16)0.f;

    if (which == 2) {
        #pragma unroll
        for (int c = 0; c < 4; ++c) {
            acc0 = __builtin_amdgcn_mfma_f32_32x32x16_bf16(xf[c], wf[0][c], acc0, 0, 0, 0);
            acc1 = __builtin_amdgcn_mfma_f32_32x32x16_bf16(xf[c], wf[1][c], acc1, 0, 0, 0);
        }
        const float b0 = bias[r31], b1 = bias[32 + r31];
        __hip_bfloat16* dst = vf + (size_t)(bx >> 1)*4096 + (bx & 1)*1024
                                 + r31*8 + 4*hi;
        #pragma unroll
        for (int g = 0; g < 4; ++g) {
            u32x2 p0 = { cvt_pk_bf16(acc0[4*g]   + b0, acc0[4*g+1] + b0),
                         cvt_pk_bf16(acc0[4*g+2] + b0, acc0[4*g+3] + b0) };
            *(s16x4*)(dst + (g >> 1)*512 + (g & 1)*256) = __builtin_bit_cast(s16x4, p0);
            u32x2 p1 = { cvt_pk_bf16(acc1[4*g]   + b1, acc1[4*g+1] + b1),
                         cvt_pk_bf16(acc1[4*g+2] + b1, acc1[4*g+3] + b1) };
            *(s16x4*)(dst + 2048 + (g >> 1)*512 + (g & 1)*256) = __builtin_bit_cast(s16x4, p1);
        }
    } else {
        #pragma unroll
        for (int c = 0; c < 4; ++c) {
            acc0 = __builtin_amdgcn_mfma_f32_32x32x16_bf16(wf[0][c], xf[c], acc0, 0, 0, 0);
            acc1 = __builtin_amdgcn_mfma_f32_32x32x16_bf16(wf[1][c], xf[c], acc1, 0, 0, 0);
        }
        const float* sc = (which == 0) ? qw : kw;
        const float cf = (which == 0) ? (0.015625f * 1.44269504088896f) : 0.015625f;
        __hip_bfloat16* dst = ((which == 0) ? qf : kf) + (size_t)bx*2048 + r31*8 + 4*hi;
        #pragma unroll
        for (int dt = 0; dt < 2; ++dt) {
            const f32x16 acc = dt ? acc1 : acc0;
            #pragma unroll
            for (int g = 0; g < 4; ++g) {
                const int dbase = 32*dt + 8*g + 4*hi;
                float4 b4 = *(const float4*)(bias + dbase);
                float4 s4 = *(const float4*)(sc + dbase);
                float v0 = (acc[4*g+0] + b4.x) * (s4.x * cf);
                float v1 = (acc[4*g+1] + b4.y) * (s4.y * cf);
                float v2 = (acc[4*g+2] + b4.z) * (s4.z * cf);
                float v3 = (acc[4*g+3] + b4.w) * (s4.w * cf);
                u32x2 p = { cvt_pk_bf16(v0, v1), cvt_pk_bf16(v2, v3) };
                *(s16x4*)(dst + (4*dt + g)*256) = __builtin_bit_cast(s16x4, p);
            }
        }
    }
}

// ---------------------------------------------------------------------------
// Flash attention r9: 512-thread blocks = 8 q-waves (256 q-rows), K/V staged
// through LDS once per block-iter (8x less global K/V traffic). LDS image is
// a VERBATIM linear copy of the frag-major global layout -> all fragment
// addresses identical to the validated r8 kernel, rebased onto LDS.
// Per iter: wave wv stages 1KB of K and 1KB of V via global_load_lds(16B);
// barrier; all waves ds_read_b128 frags (contiguous 1KB wave reads,
// conflict-free); swapped QK^T, no-max softmax (LOG2E folded into Q'),
// cvt_pk+permlane32_swap P pack, PV. 2 barriers/iter.
// Grid = 64*nsplit: b=bid&3, qblk=(bid>>2)&15, split=bid>>6; qwi=qblk*8+wv.
// ---------------------------------------------------------------------------
__global__ __launch_bounds__(512, 4) void attn_kernel(
    const __hip_bfloat16* __restrict__ qf, const __hip_bfloat16* __restrict__ kf,
    const __hip_bfloat16* __restrict__ vf,
    float* __restrict__ opart, float* __restrict__ lpart,
    float* __restrict__ outdirect, int nsplit)
{
    __shared__ __hip_bfloat16 Klds[4096];   // 8 KB: K-tile, frag-major linear
    __shared__ __hip_bfloat16 Vlds[4096];   // 8 KB: V-tile, frag-major linear

    const int tid  = threadIdx.x;
    const int lane = tid & 63;
    const int wv   = tid >> 6;                          // 0..7
    const int r31 = lane & 31, hi = lane >> 5;
    const int bid = blockIdx.x;
    const int b     = bid & 3;
    const int qblk  = (bid >> 2) & 15;                  // 16 q-blocks of 256 rows
    const int split = bid >> 6;
    const int qwi   = qblk * 8 + wv;                    // q-wave 0..127

    const __hip_bfloat16* qb = qf + (size_t)b*PERB;
    const __hip_bfloat16* kb = kf + (size_t)b*PERB;
    const __hip_bfloat16* vb = vf + (size_t)b*PERB;

    // Q B-frags: contiguous 1KB per c (register-resident)
    const __hip_bfloat16* qr = qb + (size_t)qwi*2048 + hi*256 + r31*8;
    s16x8 bQ[4];
    #pragma unroll
    for (int c = 0; c < 4; ++c) bQ[c] = *(const s16x8*)(qr + c*512);

    f32x16 O0 = (f32x16)0.f, O1 = (f32x16)0.f;          // O^T, d-halves
    float l = 0.f;

    const int span  = NS / nsplit;
    const int tbeg  = split * span;
    const int iters = span >> 6;

    for (int it = 0; it < iters; ++it) {
        const int tb = tbeg + (it << 6);

        __syncthreads();    // previous iter's LDS reads complete
        // stage K-tile (8KB) + V-tile (8KB): wave wv stages chunk wv of each
        gload_lds16(kb + (size_t)(tb >> 5)*2048 + wv*512 + lane*8, &Klds[wv*512]);
        gload_lds16(vb + (size_t)(tb >> 6)*4096 + wv*512 + lane*8, &Vlds[wv*512]);
        __syncthreads();    // staged (compiler drains vmcnt before barrier)

        // ---- QK^T: two 32-row t-tiles, K=64 over 4 mfmas each ----
        const __hip_bfloat16* kl = Klds + hi*256 + r31*8;
        f32x16 s0 = (f32x16)0.f, s1 = (f32x16)0.f;
        #pragma unroll
        for (int c = 0; c < 4; ++c) {
            s16x8 a0 = *(const s16x8*)(kl + c*512);
            s16x8 a1 = *(const s16x8*)(kl + 2048 + c*512);
            s0 = __builtin_amdgcn_mfma_f32_32x32x16_bf16(a0, bQ[c], s0, 0, 0, 0);
            s1 = __builtin_amdgcn_mfma_f32_32x32x16_bf16(a1, bQ[c], s1, 0, 0, 0);
        }

        // ---- p = 2^s (LOG2E folded into Q'), row-sum ----
        #pragma unroll
        for (int r = 0; r < 16; ++r) { s0[r] = exp2_fast(s0[r]); s1[r] = exp2_fast(s1[r]); }
        float t0 = ((s0[0]+s0[1])+(s0[2]+s0[3])) + ((s0[4]+s0[5])+(s0[6]+s0[7]));
        float t1 = ((s0[8]+s0[9])+(s0[10]+s0[11])) + ((s0[12]+s0[13])+(s0[14]+s0[15]));
        float t2 = ((s1[0]+s1[1])+(s1[2]+s1[3])) + ((s1[4]+s1[5])+(s1[6]+s1[7]));
        float t3 = ((s1[8]+s1[9])+(s1[10]+s1[11])) + ((s1[12]+s1[13])+(s1[14]+s1[15]));
        float rs = (t0 + t1) + (t2 + t3);
        rs += __shfl_xor(rs, 32);
        l += rs;

        // ---- pack P -> bf16 dwords; permlane32_swap pairs (u=2k1, 2k1+1)
        //      -> B-frag(ks=2*tile+k1) dwords [x0',x1',y0',y1'] ----
        unsigned pw0[2][4], pw1[2][4];
        #pragma unroll
        for (int u = 0; u < 4; ++u) {
            pw0[0][u] = cvt_pk_bf16(s0[4*u],   s0[4*u+1]);
            pw1[0][u] = cvt_pk_bf16(s0[4*u+2], s0[4*u+3]);
            pw0[1][u] = cvt_pk_bf16(s1[4*u],   s1[4*u+1]);
            pw1[1][u] = cvt_pk_bf16(s1[4*u+2], s1[4*u+3]);
        }

        // ---- PV: O^T[d][q] += V^T . P^T  (V frags from LDS) ----
        const __hip_bfloat16* vl = Vlds + hi*256 + r31*8;
        #pragma unroll
        for (int ks = 0; ks < 4; ++ks) {
            const int tl = ks >> 1, k1 = ks & 1;
            unsigned x0 = pw0[tl][2*k1], y0 = pw0[tl][2*k1 + 1];
            unsigned x1 = pw1[tl][2*k1], y1 = pw1[tl][2*k1 + 1];
            asm("v_permlane32_swap_b32 %0, %1" : "+v"(x0), "+v"(y0));
            asm("v_permlane32_swap_b32 %0, %1" : "+v"(x1), "+v"(y1));
            u32x4 fv = {x0, x1, y0, y1};
            s16x8 bP = __builtin_bit_cast(s16x8, fv);
            s16x8 a0 = *(const s16x8*)(vl + ks*512);
            s16x8 a1 = *(const s16x8*)(vl + 2048 + ks*512);
            O0 = __builtin_amdgcn_mfma_f32_32x32x16_bf16(a0, bP, O0, 0, 0, 0);
            O1 = __builtin_amdgcn_mfma_f32_32x32x16_bf16(a1, bP, O1, 0, 0, 0);
        }
    }

    // ---- epilogue: O^T rows d = 8u+4hi+{0..3} (+32 for O1), col q=lane&31
    const int qrow = qwi * 32 + r31;
    const size_t gq = (size_t)b*NS + qrow;
    if (outdirect) {
        const float invl = 1.f / l;
        float* orow = outdirect + gq * ND;
        #pragma unroll
        for (int u = 0; u < 4; ++u) {
            const int d0 = 8*u + 4*hi;
            float4 w0v = {O0[4*u]*invl, O0[4*u+1]*invl, O0[4*u+2]*invl, O0[4*u+3]*invl};
            *(float4*)(orow + d0) = w0v;
            float4 w1v = {O1[4*u]*invl, O1[4*u+1]*invl, O1[4*u+2]*invl, O1[4*u+3]*invl};
            *(float4*)(orow + d0 + 32) = w1v;
        }
    } else {
        float* prow = opart + ((size_t)split*NTOK + gq) * ND;
        #pragma unroll
        for (int u = 0; u < 4; ++u) {
            const int d0 = 8*u + 4*hi;
            float4 w0v = {O0[4*u], O0[4*u+1], O0[4*u+2], O0[4*u+3]};
            *(float4*)(prow + d0) = w0v;
            float4 w1v = {O1[4*u], O1[4*u+1], O1[4*u+2], O1[4*u+3]};
            *(float4*)(prow + d0 + 32) = w1v;
        }
        if (lane < 32) lpart[(size_t)split*NTOK + gq] = l;
    }
}

// ---------------------------------------------------------------------------
// Combine KV-split partials (no max tracking): out = sum_s O_s / sum_s l_s
// ---------------------------------------------------------------------------
__global__ __launch_bounds__(256) void combine_kernel(
    const float* __restrict__ opart, const float* __restrict__ lpart,
    float* __restrict__ out, int nsplit)
{
    const int tid = threadIdx.x;
    const int r = blockIdx.x * 16 + (tid >> 4);
    const int c = (tid & 15) * 4;
    float L = 0.f;
    float4 acc = {0.f, 0.f, 0.f, 0.f};
    #pragma unroll
    for (int s = 0; s < 8; ++s) {
        if (s >= nsplit) break;
        L += lpart[(size_t)s*NTOK + r];
        float4 o = *(const float4*)(opart + ((size_t)s*NTOK + r)*ND + c);
        acc.x += o.x; acc.y += o.y; acc.z += o.z; acc.w += o.w;
    }
    const float inv = 1.f / L;
    float4 res = {acc.x*inv, acc.y*inv, acc.z*inv, acc.w*inv};
    *(float4*)(out + (size_t)r*ND + c) = res;
}

extern "C" void kernel_launch(void* const* d_in, const int* in_sizes, int n_in,
                              void* d_out, int out_size, void* d_ws, size_t ws_size,
                              hipStream_t stream) {
    (void)in_sizes; (void)n_in; (void)out_size;
    const float* q  = (const float*)d_in[0];
    const float* k  = (const float*)d_in[1];
    const float* v  = (const float*)d_in[2];
    // d_in[3] = attn_mask (1,1,1): scalar added to all scores -> softmax no-op
    const float* Wq = (const float*)d_in[4];
    const float* bq = (const float*)d_in[5];
    const float* Wk = (const float*)d_in[6];
    const float* bk = (const float*)d_in[7];
    const float* Wv = (const float*)d_in[8];
    const float* bv = (const float*)d_in[9];
    const float* qw = (const float*)d_in[10];
    const float* kw = (const float*)d_in[11];

    __hip_bfloat16* qfb = (__hip_bfloat16*)d_ws;            // 2 MB
    __hip_bfloat16* kfb = qfb + (size_t)NTOK*ND;            // 2 MB
    __hip_bfloat16* vfb = kfb + (size_t)NTOK*ND;            // 2 MB
    float* rest = (float*)(vfb + (size_t)NTOK*ND);

    auto need = [](int s) {
        return (size_t)NTOK*ND*2*3 + (size_t)s*NTOK*(ND*4 + 4);
    };
    const int nsplit = (ws_size >= need(8)) ? 8
                     : (ws_size >= need(4)) ? 4
                     : (ws_size >= need(2)) ? 2 : 1;

    float* opart = rest;
    float* lp = opart + (size_t)nsplit*NTOK*ND;

    proj_kernel<<<dim3(512, 3), 64, 0, stream>>>(q, k, v, Wq, bq, Wk, bk, Wv, bv,
                                                 qw, kw, qfb, kfb, vfb);
    attn_kernel<<<dim3(64*nsplit), 512, 0, stream>>>(
        qfb, kfb, vfb, opart, lp,
        (nsplit == 1) ? (float*)d_out : nullptr, nsplit);
    if (nsplit > 1)
        combine_kernel<<<dim3(NTOK/16), 256, 0, stream>>>(opart, lp,
                                                          (float*)d_out, nsplit);
}